// Round 7
// baseline (278.887 us; speedup 1.0000x reference)
//
#include <hip/hip_runtime.h>
#include <climits>

// StreamingRhythmProjector: B=4096 rows x U=2048 units.
// R15 = R14 (wave-per-row, zero barriers, zero LDS) minus the spill.
// R14 verdict: removing the block-barrier convoy raised achieved HBM BW
// 2.35 -> 2.95 TB/s (theory confirmed), but the 64-float/thread sr_/sc_
// carry arrays spilled to scratch (+45 MB write, +20 MB fetch) and ate the
// win. R15 deletes the carry state entirely:
//  - pass 1 accumulates ONLY the two sums (no per-element storage).
//  - pass 2 RE-READS the row (just fetched -> L2/L3-resident; FETCH_SIZE
//    counts HBM only, so no extra HBM traffic) and recomputes sr/sc before
//    scaling + stores. Extra VALU ~2x pass-1 is free at 10% VALUBusy.
//  - per-thread live state = 2-deep pipeline buffers (~32 regs) -> no
//    spill possible. launch_bounds(256,4) = 128-VGPR cap, 16 waves/CU.
// Predictions: WRITE back to ~99 MB (>110 = spill alarm), FETCH ~46-55 MB,
// dur 72 -> 47-55us at ~3 TB/s.

constexpr int UNITS = 2048;
constexpr int BLOCK = 256;
constexpr int ROWS_PER_BLOCK = 4;  // one per wave

typedef float f32x4 __attribute__((ext_vector_type(4)));

static __device__ __forceinline__ float waveSum(float v) {
#pragma unroll
  for (int m = 1; m < 64; m <<= 1) v += __shfl_xor(v, m, 64);
  return v;  // all lanes hold the sum
}

__global__ __launch_bounds__(BLOCK, 4) void rhythm_kernel(
    const float* __restrict__ dur_anchor,    // [B,U]
    const float* __restrict__ unit_mask,     // [B,U] prefix mask (0/1)
    const float* __restrict__ speech_budget, // [B]
    const float* __restrict__ pause_budget,  // [B]
    const float* __restrict__ dur_logratio,  // [B,U]
    const float* __restrict__ pause_weight,  // [B,U]
    const float* __restrict__ boundary,      // [B,U]
    const float* __restrict__ phase_ptr,     // [B]
    const float* __restrict__ backlog,       // [B]
    const float* __restrict__ clock_delta,   // [B]
    const int*   __restrict__ commit_front,  // [B]
    const int*   __restrict__ open_run,      // [B,U]
    float* __restrict__ out,                 // f32, 3*B*U + 4*B
    int B) {
  const int t = threadIdx.x;
  const int wv = t >> 6, ln = t & 63;
  const int row = blockIdx.x * ROWS_PER_BLOCK + wv;
  if (row >= B) return;  // whole-wave uniform; no barriers anywhere
  const size_t base = (size_t)row * UNITS;

  // per-row scalars
  const int prev = commit_front[row];
  const float sb = speech_budget[row];
  const float pb = pause_budget[row];

  // ---- probe `visible` from the prefix mask ----
  int visible;
  {
    const float v1 = unit_mask[base + 64 * ((ln < 32) ? ln : 0) + 63];
    const int c1 = __popcll(__ballot((ln < 32) && (v1 > 0.5f)));
    if (c1 == 32) {
      visible = 2048;
    } else {
      const int s = 64 * c1;                       // s <= 1984, s+63 <= 2047
      const float v2 = unit_mask[base + s + ln];
      visible = s + __popcll(__ballot(v2 > 0.5f));
    }
  }

  // ---- early-exit scan for first open index in [0, visible) ----
  int min_open = INT_MAX;
  for (int cs = 0; cs < visible; cs += 256) {
    const int e = cs + 4 * ln;                     // e+3 <= 2047 always
    int4 o4 = make_int4(0, 0, 0, 0);
    if (e < visible) o4 = *(const int4*)(open_run + base + e);
    int lm = INT_MAX;
    if (o4.w > 0 && e + 3 < visible) lm = e + 3;
    if (o4.z > 0 && e + 2 < visible) lm = e + 2;
    if (o4.y > 0 && e + 1 < visible) lm = e + 1;
    if (o4.x > 0 && e < visible) lm = e;
    const unsigned long long bb = __ballot(lm != INT_MAX);
    if (bb) {  // lanes ascend in idx; first set lane holds the chunk min
      min_open = __shfl(lm, (int)__ffsll(bb) - 1, 64);
      break;
    }
  }

  // ---- commit candidate + bval (issued before pass 1; resolves under it) --
  const int closed = (min_open == INT_MAX) ? visible : min_open;
  const int cand0 = min(max(visible - 2, 0), closed);  // TAIL_HOLD_UNITS
  const float bval = boundary[base + min(max(cand0 - 1, 0), UNITS - 1)];

  // ---- shared 2-deep prefetch pipeline over 8 chunks x 256 elems ----
  float4 Ab[2], Lb[2], Pb[2], Bb[2];
  auto loadChunk = [&](int c, int slot) {
    const int e = c * 256 + 4 * ln;
    const float4 z = {0.f, 0.f, 0.f, 0.f};
    Ab[slot] = z; Lb[slot] = z; Pb[slot] = z; Bb[slot] = z;
    if (e < visible) {
      Ab[slot] = *(const float4*)(dur_anchor   + base + e);
      Lb[slot] = *(const float4*)(dur_logratio + base + e);
      Pb[slot] = *(const float4*)(pause_weight + base + e);
      Bb[slot] = *(const float4*)(boundary     + base + e);
    }
  };

  // ---- pass 1: sums ONLY (no per-element carry -> no spill) ----
  float sum_sr = 0.f, sum_sc = 0.f;
  loadChunk(0, 0);
  loadChunk(1, 1);
#pragma unroll
  for (int c = 0; c < 8; ++c) {
    const float4 a4 = Ab[c & 1];
    const float4 l4 = Lb[c & 1];
    const float4 p4 = Pb[c & 1];
    const float4 b4 = Bb[c & 1];
    if (c + 2 < 8) loadChunk(c + 2, c & 1);  // refill slot, 2 ahead
    const int e = c * 256 + 4 * ln;
    const float av[4] = {a4.x, a4.y, a4.z, a4.w};
    const float lv[4] = {l4.x, l4.y, l4.z, l4.w};
    const float pv[4] = {p4.x, p4.y, p4.z, p4.w};
    const float bv[4] = {b4.x, b4.y, b4.z, b4.w};
#pragma unroll
    for (int j = 0; j < 4; ++j) {
      const float m = (e + j < visible) ? 1.0f : 0.0f;
      const float a = fmaxf(av[j], 1.0f);                      // MIN_SPEECH_FRAMES
      sum_sr += fmaxf(fminf(a * __expf(lv[j]), 3.0f * a), 1.0f) * m;
      sum_sc += fmaxf(pv[j], 0.0f) * (0.5f + bv[j]) * m;
    }
  }

  // ---- totals: pure in-wave reduction (NO barrier, NO LDS) ----
  const float ts = waveSum(sum_sr);
  const float tc = waveSum(sum_sc);
  const float tm = (float)visible;  // sum of prefix mask, exact

  // ---- commit frontier finalize ----
  int cand = cand0;
  if (cand0 > 0 && cand0 < visible && bval < 0.45f)   // BOUNDARY_COMMIT_THRESHOLD
    cand = max(prev, cand0 - 1);
  const int commit = max(prev, cand);

  const float sscale = sb / fmaxf(ts, 1e-6f);
  const bool usefb = !(tc > 0.0f);
  const float pscale = pb / fmaxf(tc, 1e-6f);
  const float fbw = pb / fmaxf(tm, 1.0f);
  // analytic effective total (linearity): Sum eff = sscale*ts + pscale*tc
  const float eff_tot = usefb ? (sscale * ts + fbw * tm) : (sscale * ts + pscale * tc);

  // ---- pass 2: re-read (L2/L3-hot), recompute sr/sc, scale, store ----
  float* __restrict__ out_speech = out;
  float* __restrict__ out_pause  = out + (size_t)B * UNITS;
  float* __restrict__ out_eff    = out + 2 * (size_t)B * UNITS;

  loadChunk(0, 0);
  loadChunk(1, 1);
#pragma unroll
  for (int c = 0; c < 8; ++c) {
    const float4 a4 = Ab[c & 1];
    const float4 l4 = Lb[c & 1];
    const float4 p4 = Pb[c & 1];
    const float4 b4 = Bb[c & 1];
    if (c + 2 < 8) loadChunk(c + 2, c & 1);
    const int e = c * 256 + 4 * ln;
    const float av[4] = {a4.x, a4.y, a4.z, a4.w};
    const float lv[4] = {l4.x, l4.y, l4.z, l4.w};
    const float pv[4] = {p4.x, p4.y, p4.z, p4.w};
    const float bv[4] = {b4.x, b4.y, b4.z, b4.w};
    f32x4 s4, q4, e4;
#pragma unroll
    for (int j = 0; j < 4; ++j) {
      const float m = (e + j < visible) ? 1.0f : 0.0f;
      const float a = fmaxf(av[j], 1.0f);
      const float sr = fmaxf(fminf(a * __expf(lv[j]), 3.0f * a), 1.0f) * m;
      const float sc = fmaxf(pv[j], 0.0f) * (0.5f + bv[j]) * m;
      const float speech = sr * sscale;
      const float pause = usefb ? (m * fbw) : (sc * pscale);
      s4[j] = speech;
      q4[j] = pause;
      e4[j] = speech + pause;
    }
    *(f32x4*)(out_speech + base + e) = s4;
    *(f32x4*)(out_pause  + base + e) = q4;
    *(f32x4*)(out_eff    + base + e) = e4;
  }

  // ---- per-wave tail: tiny [prev,commit) range sums (cache-hot re-read) ----
  float src_rng = 0.f, eff_rng = 0.f;
  if (commit > prev) {
    for (int i = prev + ln; i < commit; i += 64) {     // all i < visible here
      const float a = dur_anchor[base + i];
      const float l = dur_logratio[base + i];
      const float p = pause_weight[base + i];
      const float bo = boundary[base + i];
      src_rng += a;
      const float aa = fmaxf(a, 1.0f);
      const float sr = fmaxf(fminf(aa * __expf(l), 3.0f * aa), 1.0f);
      const float sc = fmaxf(p, 0.0f) * (0.5f + bo);
      eff_rng += sr * sscale + (usefb ? fbw : sc * pscale);
    }
  }
  const float srcp = waveSum(src_rng);
  const float execp = waveSum(eff_rng);

  if (ln == 0) {
    const float pp = phase_ptr[row];
    const float bl = backlog[row];
    const float cd = clock_delta[row];
    const bool adv = commit > prev;
    const float nclock = adv ? (cd + (execp - srcp)) : cd;
    const float nback = adv ? fmaxf(nclock, 0.0f) : bl;
    const float vt = fmaxf(eff_tot, 1.0f);
    const float nphase =
        adv ? fminf(fmaxf(pp + execp / vt, 0.0f), 1.0f) : pp;
    const size_t o = 3 * (size_t)B * UNITS;
    out[o + row] = (float)commit;
    out[o + (size_t)B + row] = nphase;
    out[o + 2 * (size_t)B + row] = nback;
    out[o + 3 * (size_t)B + row] = nclock;
  }
}

extern "C" void kernel_launch(void* const* d_in, const int* in_sizes, int n_in,
                              void* d_out, int out_size, void* d_ws, size_t ws_size,
                              hipStream_t stream) {
  const int B = in_sizes[7];  // phase_ptr length
  const int nb = (B + ROWS_PER_BLOCK - 1) / ROWS_PER_BLOCK;
  rhythm_kernel<<<dim3(nb), dim3(BLOCK), 0, stream>>>(
      (const float*)d_in[0],   // dur_anchor_src
      (const float*)d_in[1],   // unit_mask
      (const float*)d_in[2],   // speech_budget_win
      (const float*)d_in[3],   // pause_budget_win
      (const float*)d_in[4],   // dur_logratio_unit
      (const float*)d_in[5],   // pause_weight_unit
      (const float*)d_in[6],   // boundary_latent
      (const float*)d_in[7],   // phase_ptr
      (const float*)d_in[8],   // backlog
      (const float*)d_in[9],   // clock_delta
      (const int*)d_in[10],    // commit_frontier
      (const int*)d_in[11],    // open_run_mask
      (float*)d_out, B);
}

// Round 9
// 258.768 us; speedup vs baseline: 1.0777x; 1.0777x over previous
//
#include <hip/hip_runtime.h>
#include <climits>

// StreamingRhythmProjector: B=4096 rows x U=2048 units.
// R16 (resubmit after infra timeout) = R14's architecture (wave-per-row,
// ZERO barriers, ZERO LDS, single read pass, carry sr/sc in registers)
// with the compiler trap removed.
// Evidence: R14 and R15 BOTH showed WRITE ~140-144 MB and VGPR_Count=64.
// R15 had no carry arrays, so the traffic wasn't the sr_/sc_ spill — it is
// the Ab[2]/Lb[2]/... pipeline ARRAYS accessed via a reference-capturing
// lambda (rule #20: array-typed locals with non-trivially-provable indexing
// get demoted to scratch; VGPR=64 with ~100 floats of nominal state is the
// tell). Scratch round-trips inflated FETCH+WRITE and sank occupancy.
// Robust positive: zero-barrier free-run sustains 2.7-3.0 TB/s vs the
// 2.35 TB/s barrier-convoy pin (R9-R13).
// R16: NO arrays, NO lambdas. All pipeline buffers and all 16 carried
// sr/sc chunks are NAMED f32x4 variables, manually unrolled via macros.
// Register audit: carry 64 + pipeline 32 + temps/sums/addr ~20 => ~116
// under the launch_bounds(256,4) 128-VGPR cap.
// Predictions: VGPR ~100-128 (discriminator!), WRITE ~99 MB, FETCH ~45-55,
// BW >= 2.9 TB/s, dur 48-56us.

constexpr int UNITS = 2048;
constexpr int BLOCK = 256;
constexpr int ROWS_PER_BLOCK = 4;  // one per wave

typedef float f32x4 __attribute__((ext_vector_type(4)));

static __device__ __forceinline__ float waveSum(float v) {
#pragma unroll
  for (int m = 1; m < 64; m <<= 1) v += __shfl_xor(v, m, 64);
  return v;  // all lanes hold the sum
}

// Load chunk c (4 arrays x f32x4) into NAMED variables. Zero if masked out.
#define LOADC(c, A, L, P, Bv)                                         \
  {                                                                   \
    const int e_ = (c) * 256 + 4 * ln;                                \
    if (e_ < visible) {                                               \
      A  = *(const f32x4*)(dur_anchor   + base + e_);                 \
      L  = *(const f32x4*)(dur_logratio + base + e_);                 \
      P  = *(const f32x4*)(pause_weight + base + e_);                 \
      Bv = *(const f32x4*)(boundary     + base + e_);                 \
    } else {                                                          \
      A = z4; L = z4; P = z4; Bv = z4;                                \
    }                                                                 \
  }

#define COMP1(j, eb_, A, L, P, Bv, SR, SC)                            \
  {                                                                   \
    const float m_ = ((eb_) + (j) < visible) ? 1.0f : 0.0f;           \
    const float a_ = fmaxf((A)[j], 1.0f);                             \
    const float srv =                                                 \
        fmaxf(fminf(a_ * __expf((L)[j]), 3.0f * a_), 1.0f) * m_;      \
    const float scv = fmaxf((P)[j], 0.0f) * (0.5f + (Bv)[j]) * m_;    \
    (SR)[j] = srv;                                                    \
    (SC)[j] = scv;                                                    \
    sum_sr += srv;                                                    \
    sum_sc += scv;                                                    \
  }

// Consume a pipeline set into carry regs SR/SC (+sums); set is free after.
#define COMPC(c, A, L, P, Bv, SR, SC)                                 \
  {                                                                   \
    const int eb_ = (c) * 256 + 4 * ln;                               \
    COMP1(0, eb_, A, L, P, Bv, SR, SC)                                \
    COMP1(1, eb_, A, L, P, Bv, SR, SC)                                \
    COMP1(2, eb_, A, L, P, Bv, SR, SC)                                \
    COMP1(3, eb_, A, L, P, Bv, SR, SC)                                \
  }

// Pass-2: scale carried values and store 3 outputs for chunk c.
#define STOREC(c, SR, SC)                                             \
  {                                                                   \
    const int eb_ = (c) * 256 + 4 * ln;                               \
    f32x4 s4, q4, e4;                                                 \
    {                                                                 \
      const float m0 = (eb_ + 0 < visible) ? 1.0f : 0.0f;             \
      const float m1 = (eb_ + 1 < visible) ? 1.0f : 0.0f;             \
      const float m2 = (eb_ + 2 < visible) ? 1.0f : 0.0f;             \
      const float m3 = (eb_ + 3 < visible) ? 1.0f : 0.0f;             \
      s4[0] = (SR)[0] * sscale;                                       \
      s4[1] = (SR)[1] * sscale;                                       \
      s4[2] = (SR)[2] * sscale;                                       \
      s4[3] = (SR)[3] * sscale;                                       \
      q4[0] = usefb ? (m0 * fbw) : ((SC)[0] * pscale);                \
      q4[1] = usefb ? (m1 * fbw) : ((SC)[1] * pscale);                \
      q4[2] = usefb ? (m2 * fbw) : ((SC)[2] * pscale);                \
      q4[3] = usefb ? (m3 * fbw) : ((SC)[3] * pscale);                \
      e4[0] = s4[0] + q4[0];                                          \
      e4[1] = s4[1] + q4[1];                                          \
      e4[2] = s4[2] + q4[2];                                          \
      e4[3] = s4[3] + q4[3];                                          \
    }                                                                 \
    *(f32x4*)(out_speech + base + eb_) = s4;                          \
    *(f32x4*)(out_pause  + base + eb_) = q4;                          \
    *(f32x4*)(out_eff    + base + eb_) = e4;                          \
  }

__global__ __launch_bounds__(BLOCK, 4) void rhythm_kernel(
    const float* __restrict__ dur_anchor,    // [B,U]
    const float* __restrict__ unit_mask,     // [B,U] prefix mask (0/1)
    const float* __restrict__ speech_budget, // [B]
    const float* __restrict__ pause_budget,  // [B]
    const float* __restrict__ dur_logratio,  // [B,U]
    const float* __restrict__ pause_weight,  // [B,U]
    const float* __restrict__ boundary,      // [B,U]
    const float* __restrict__ phase_ptr,     // [B]
    const float* __restrict__ backlog,       // [B]
    const float* __restrict__ clock_delta,   // [B]
    const int*   __restrict__ commit_front,  // [B]
    const int*   __restrict__ open_run,      // [B,U]
    float* __restrict__ out,                 // f32, 3*B*U + 4*B
    int B) {
  const int t = threadIdx.x;
  const int wv = t >> 6, ln = t & 63;
  const int row = blockIdx.x * ROWS_PER_BLOCK + wv;
  if (row >= B) return;  // whole-wave uniform; no barriers anywhere
  const size_t base = (size_t)row * UNITS;
  const f32x4 z4 = {0.f, 0.f, 0.f, 0.f};

  // per-row scalars
  const int prev = commit_front[row];
  const float sb = speech_budget[row];
  const float pb = pause_budget[row];

  // ---- probe `visible` from the prefix mask ----
  int visible;
  {
    const float v1 = unit_mask[base + 64 * ((ln < 32) ? ln : 0) + 63];
    const int c1 = __popcll(__ballot((ln < 32) && (v1 > 0.5f)));
    if (c1 == 32) {
      visible = 2048;
    } else {
      const int s = 64 * c1;                       // s <= 1984, s+63 <= 2047
      const float v2 = unit_mask[base + s + ln];
      visible = s + __popcll(__ballot(v2 > 0.5f));
    }
  }

  // ---- early-exit scan for first open index in [0, visible) ----
  int min_open = INT_MAX;
  for (int cs = 0; cs < visible; cs += 256) {
    const int e = cs + 4 * ln;                     // e+3 <= 2047 always
    int4 o4 = make_int4(0, 0, 0, 0);
    if (e < visible) o4 = *(const int4*)(open_run + base + e);
    int lm = INT_MAX;
    if (o4.w > 0 && e + 3 < visible) lm = e + 3;
    if (o4.z > 0 && e + 2 < visible) lm = e + 2;
    if (o4.y > 0 && e + 1 < visible) lm = e + 1;
    if (o4.x > 0 && e < visible) lm = e;
    const unsigned long long bb = __ballot(lm != INT_MAX);
    if (bb) {  // lanes ascend in idx; first set lane holds the chunk min
      min_open = __shfl(lm, (int)__ffsll(bb) - 1, 64);
      break;
    }
  }

  // ---- commit candidate + bval (issued before pass 1; resolves under it) --
  const int closed = (min_open == INT_MAX) ? visible : min_open;
  const int cand0 = min(max(visible - 2, 0), closed);  // TAIL_HOLD_UNITS
  const float bval = boundary[base + min(max(cand0 - 1, 0), UNITS - 1)];

  // ---- pass 1: single read pass, NAMED 2-deep pipeline, NAMED carry ----
  f32x4 A0, L0, P0, B0, A1, L1, P1, B1;                 // pipeline sets
  f32x4 sr0, sr1, sr2, sr3, sr4, sr5, sr6, sr7;         // carried speech_raw
  f32x4 sc0, sc1, sc2, sc3, sc4, sc5, sc6, sc7;         // carried pause score
  float sum_sr = 0.f, sum_sc = 0.f;

  LOADC(0, A0, L0, P0, B0)
  LOADC(1, A1, L1, P1, B1)
  { f32x4 a = A0, l = L0, p = P0, b = B0; LOADC(2, A0, L0, P0, B0) COMPC(0, a, l, p, b, sr0, sc0) }
  { f32x4 a = A1, l = L1, p = P1, b = B1; LOADC(3, A1, L1, P1, B1) COMPC(1, a, l, p, b, sr1, sc1) }
  { f32x4 a = A0, l = L0, p = P0, b = B0; LOADC(4, A0, L0, P0, B0) COMPC(2, a, l, p, b, sr2, sc2) }
  { f32x4 a = A1, l = L1, p = P1, b = B1; LOADC(5, A1, L1, P1, B1) COMPC(3, a, l, p, b, sr3, sc3) }
  { f32x4 a = A0, l = L0, p = P0, b = B0; LOADC(6, A0, L0, P0, B0) COMPC(4, a, l, p, b, sr4, sc4) }
  { f32x4 a = A1, l = L1, p = P1, b = B1; LOADC(7, A1, L1, P1, B1) COMPC(5, a, l, p, b, sr5, sc5) }
  COMPC(6, A0, L0, P0, B0, sr6, sc6)
  COMPC(7, A1, L1, P1, B1, sr7, sc7)

  // ---- totals: pure in-wave reduction (NO barrier, NO LDS) ----
  const float ts = waveSum(sum_sr);
  const float tc = waveSum(sum_sc);
  const float tm = (float)visible;  // sum of prefix mask, exact

  // ---- commit frontier finalize ----
  int cand = cand0;
  if (cand0 > 0 && cand0 < visible && bval < 0.45f)   // BOUNDARY_COMMIT_THRESHOLD
    cand = max(prev, cand0 - 1);
  const int commit = max(prev, cand);

  const float sscale = sb / fmaxf(ts, 1e-6f);
  const bool usefb = !(tc > 0.0f);
  const float pscale = pb / fmaxf(tc, 1e-6f);
  const float fbw = pb / fmaxf(tm, 1.0f);
  // analytic effective total (linearity): Sum eff = sscale*ts + pscale*tc
  const float eff_tot = usefb ? (sscale * ts + fbw * tm) : (sscale * ts + pscale * tc);

  // ---- pass 2: scale carried regs + stores (no loads at all) ----
  float* __restrict__ out_speech = out;
  float* __restrict__ out_pause  = out + (size_t)B * UNITS;
  float* __restrict__ out_eff    = out + 2 * (size_t)B * UNITS;

  STOREC(0, sr0, sc0)
  STOREC(1, sr1, sc1)
  STOREC(2, sr2, sc2)
  STOREC(3, sr3, sc3)
  STOREC(4, sr4, sc4)
  STOREC(5, sr5, sc5)
  STOREC(6, sr6, sc6)
  STOREC(7, sr7, sc7)

  // ---- per-wave tail: tiny [prev,commit) range sums (cache-hot re-read) ----
  float src_rng = 0.f, eff_rng = 0.f;
  if (commit > prev) {
    for (int i = prev + ln; i < commit; i += 64) {     // all i < visible here
      const float a = dur_anchor[base + i];
      const float l = dur_logratio[base + i];
      const float p = pause_weight[base + i];
      const float bo = boundary[base + i];
      src_rng += a;
      const float aa = fmaxf(a, 1.0f);
      const float sr = fmaxf(fminf(aa * __expf(l), 3.0f * aa), 1.0f);
      const float sc = fmaxf(p, 0.0f) * (0.5f + bo);
      eff_rng += sr * sscale + (usefb ? fbw : sc * pscale);
    }
  }
  const float srcp = waveSum(src_rng);
  const float execp = waveSum(eff_rng);

  if (ln == 0) {
    const float pp = phase_ptr[row];
    const float bl = backlog[row];
    const float cd = clock_delta[row];
    const bool adv = commit > prev;
    const float nclock = adv ? (cd + (execp - srcp)) : cd;
    const float nback = adv ? fmaxf(nclock, 0.0f) : bl;
    const float vt = fmaxf(eff_tot, 1.0f);
    const float nphase =
        adv ? fminf(fmaxf(pp + execp / vt, 0.0f), 1.0f) : pp;
    const size_t o = 3 * (size_t)B * UNITS;
    out[o + row] = (float)commit;
    out[o + (size_t)B + row] = nphase;
    out[o + 2 * (size_t)B + row] = nback;
    out[o + 3 * (size_t)B + row] = nclock;
  }
}

extern "C" void kernel_launch(void* const* d_in, const int* in_sizes, int n_in,
                              void* d_out, int out_size, void* d_ws, size_t ws_size,
                              hipStream_t stream) {
  const int B = in_sizes[7];  // phase_ptr length
  const int nb = (B + ROWS_PER_BLOCK - 1) / ROWS_PER_BLOCK;
  rhythm_kernel<<<dim3(nb), dim3(BLOCK), 0, stream>>>(
      (const float*)d_in[0],   // dur_anchor_src
      (const float*)d_in[1],   // unit_mask
      (const float*)d_in[2],   // speech_budget_win
      (const float*)d_in[3],   // pause_budget_win
      (const float*)d_in[4],   // dur_logratio_unit
      (const float*)d_in[5],   // pause_weight_unit
      (const float*)d_in[6],   // boundary_latent
      (const float*)d_in[7],   // phase_ptr
      (const float*)d_in[8],   // backlog
      (const float*)d_in[9],   // clock_delta
      (const int*)d_in[10],    // commit_frontier
      (const int*)d_in[11],    // open_run_mask
      (float*)d_out, B);
}